// Round 7
// baseline (1617.974 us; speedup 1.0000x reference)
//
#include <hip/hip_runtime.h>
#include <hip/hip_bf16.h>

// GNN: 5-layer GCN on MI355X. Round 7: kill the sup4 atomic scatter.
// Round-6 forensics: gemm3_w4's 16M device-scope f32 atomicAdds (32 serialized L2 RMWs
// per output element) were ~400us of the 503us; bank-conflict fix (50x counter drop)
// only bought 40us. Now each (col-block, wc-half) stores its [128,10] partial to a
// private slot of sup4p[32][N*10] (plain stores), and sup4_reduce sums the 32 slots.
// Everything else unchanged from round 6 (XOR-swizzled MFMA GEMMs, CSR-gather SpMM).

#define SCAN_CHUNK 512
#define BM 128
#define BN 128
#define BK 64

typedef __attribute__((ext_vector_type(4))) float f32x4;
typedef __attribute__((ext_vector_type(8))) __bf16 bf16x8;
typedef __attribute__((ext_vector_type(8))) short s16x8;

__device__ __forceinline__ bf16x8 as_bf(s16x8 v) { union { s16x8 s; bf16x8 b; } u; u.s = v; return u.b; }
__device__ __forceinline__ ushort f2bf(float f) {
    uint u = __float_as_uint(f);
    return (ushort)((u + 0x7FFFu + ((u >> 16) & 1u)) >> 16);   // RNE
}
__device__ __forceinline__ float bf2f(ushort s) { return __uint_as_float(((uint)s) << 16); }

#define GLL16(g, l)                                                                 \
    __builtin_amdgcn_global_load_lds((const __attribute__((address_space(1))) void*)(g), \
                                     (__attribute__((address_space(3))) void*)(l), 16, 0, 0)

// ---------------- support GEMM: C[M,512]bf16 = A[M,512]bf16 @ Bt[512,512]bf16^T ------
__global__ __launch_bounds__(256) void gemm_sup(const ushort* __restrict__ A,
                                                const ushort* __restrict__ Bt,
                                                ushort* __restrict__ C, int M) {
    __shared__ ushort As[BM * BK];
    __shared__ ushort Bs[BN * BK];
    int tid = threadIdx.x;
    int w = tid >> 6, l = tid & 63;
    int row0 = blockIdx.y * BM, col0 = blockIdx.x * BN;
    int wr = (w >> 1) * 64, wc = (w & 1) * 64;
    f32x4 acc[4][4] = {};
    int arow_off = w * 8 + (l >> 3);
    int acol = (((l & 7) ^ (l >> 3)) << 3);   // swizzled global source chunk
    for (int k0 = 0; k0 < 512; k0 += BK) {
        __syncthreads();
#pragma unroll
        for (int i = 0; i < 4; ++i) {
            int ar = row0 + arow_off + i * 32;
            if (ar >= M) ar = M - 1;
            GLL16(A + (size_t)ar * 512 + k0 + acol, &As[(w * 8 + i * 32) * BK]);
            GLL16(Bt + (size_t)(col0 + arow_off + i * 32) * 512 + k0 + acol, &Bs[(w * 8 + i * 32) * BK]);
        }
        __syncthreads();
#pragma unroll
        for (int s = 0; s < 2; ++s) {
            int cswz = (((s * 4 + (l >> 4)) ^ (l & 7)) << 3);   // swizzled read chunk
            bf16x8 af[4], bfr[4];
#pragma unroll
            for (int m = 0; m < 4; ++m)
                af[m] = as_bf(*(const s16x8*)&As[(wr + m * 16 + (l & 15)) * BK + cswz]);
#pragma unroll
            for (int n = 0; n < 4; ++n)
                bfr[n] = as_bf(*(const s16x8*)&Bs[(wc + n * 16 + (l & 15)) * BK + cswz]);
#pragma unroll
            for (int m = 0; m < 4; ++m)
#pragma unroll
                for (int n = 0; n < 4; ++n)
                    acc[m][n] = __builtin_amdgcn_mfma_f32_16x16x32_bf16(af[m], bfr[n], acc[m][n], 0, 0, 0);
        }
    }
    int crow = (l >> 4) * 4, ccol = l & 15;
#pragma unroll
    for (int m = 0; m < 4; ++m)
#pragma unroll
        for (int n = 0; n < 4; ++n) {
            int gc = col0 + wc + n * 16 + ccol;
#pragma unroll
            for (int r = 0; r < 4; ++r) {
                int gr = row0 + wr + m * 16 + crow + r;
                if (gr < M) C[(size_t)gr * 512 + gc] = f2bf(acc[m][n][r]);
            }
        }
}

// ---------------- fused layer-3: partial = (mix(relu(g@W3), tra3)) @ W4 --------------
// A: g [M,512] bf16. Bt: Wt3 [2048,512] bf16 (pad rows zero). T: tra3 [M,2000] f32.
// W4: [2000,10] f32 (B-frag in registers). sup4p: [32][M*10] f32 private partial slots
// (slot = blockIdx.x*2 + (w&1)); no atomics.
__global__ __launch_bounds__(256) void gemm3_w4(const ushort* __restrict__ A,
                                                const ushort* __restrict__ Bt,
                                                const float* __restrict__ T,
                                                const float* __restrict__ W4,
                                                float* __restrict__ sup4p, int M) {
    __shared__ ushort lds[16384];          // 32 KB
    ushort* As   = lds;                    // [128*64] main loop
    ushort* Bs   = lds + 8192;             // [128*64]
    ushort* actS = lds;                    // [128][128] swizzled, epilogue overlay
    int tid = threadIdx.x;
    int w = tid >> 6, l = tid & 63;
    int row0 = blockIdx.y * BM, col0 = blockIdx.x * BN;
    int wr = (w >> 1) * 64, wc = (w & 1) * 64;
    int crow = (l >> 4) * 4, ccol = l & 15;

    // W4 B-fragment into registers: lane holds W4[col0+wc+s*32+(l>>4)*8 + kk][ccol]
    bf16x8 w4f[2];
    {
#pragma unroll
        for (int s = 0; s < 2; ++s) {
            s16x8 tmp;
#pragma unroll
            for (int kk = 0; kk < 8; ++kk) {
                int gk = col0 + wc + s * 32 + ((l >> 4) << 3) + kk;
                float v = (ccol < 10 && gk < 2000) ? W4[(size_t)gk * 10 + ccol] : 0.f;
                tmp[kk] = (short)f2bf(v);
            }
            w4f[s] = as_bf(tmp);
        }
    }

    f32x4 acc[4][4] = {};
    int arow_off = w * 8 + (l >> 3);
    int acol = (((l & 7) ^ (l >> 3)) << 3);
    for (int k0 = 0; k0 < 512; k0 += BK) {
        __syncthreads();
#pragma unroll
        for (int i = 0; i < 4; ++i) {
            int ar = row0 + arow_off + i * 32;
            if (ar >= M) ar = M - 1;
            GLL16(A + (size_t)ar * 512 + k0 + acol, &As[(w * 8 + i * 32) * BK]);
            GLL16(Bt + (size_t)(col0 + arow_off + i * 32) * 512 + k0 + acol, &Bs[(w * 8 + i * 32) * BK]);
        }
        __syncthreads();
#pragma unroll
        for (int s = 0; s < 2; ++s) {
            int cswz = (((s * 4 + (l >> 4)) ^ (l & 7)) << 3);
            bf16x8 af[4], bfr[4];
#pragma unroll
            for (int m = 0; m < 4; ++m)
                af[m] = as_bf(*(const s16x8*)&As[(wr + m * 16 + (l & 15)) * BK + cswz]);
#pragma unroll
            for (int n = 0; n < 4; ++n)
                bfr[n] = as_bf(*(const s16x8*)&Bs[(wc + n * 16 + (l & 15)) * BK + cswz]);
#pragma unroll
            for (int m = 0; m < 4; ++m)
#pragma unroll
                for (int n = 0; n < 4; ++n)
                    acc[m][n] = __builtin_amdgcn_mfma_f32_16x16x32_bf16(af[m], bfr[n], acc[m][n], 0, 0, 0);
        }
    }

    // epilogue: act tile (mix applied) -> LDS bf16, stride 128, same XOR swizzle
    __syncthreads();
#pragma unroll
    for (int m = 0; m < 4; ++m)
#pragma unroll
        for (int n = 0; n < 4; ++n) {
            int cl = wc + n * 16 + ccol;
            int cch = cl >> 3, clo = cl & 7;
            int gc = col0 + cl;
#pragma unroll
            for (int r = 0; r < 4; ++r) {
                int rl = wr + m * 16 + crow + r;
                int gr = row0 + rl;
                float v = 0.f;
                if (gr < M && gc < 2000)
                    v = 0.5f * fmaxf(acc[m][n][r], 0.f) + 0.5f * T[(size_t)gr * 2000 + gc];
                actS[rl * 128 + (((cch ^ (rl & 7)) << 3) | clo)] = f2bf(v);
            }
        }
    __syncthreads();

    // stage 2: act[128r x 128k] @ W4-frag; each wave: its 64 rows x its 64-k half
    f32x4 acc2[4] = {};
#pragma unroll
    for (int s = 0; s < 2; ++s) {
        int chunk = (wc + s * 32 + ((l >> 4) << 3)) >> 3;
#pragma unroll
        for (int m = 0; m < 4; ++m) {
            int row = wr + m * 16 + ccol;
            bf16x8 af = as_bf(*(const s16x8*)&actS[row * 128 + ((chunk ^ (row & 7)) << 3)]);
            acc2[m] = __builtin_amdgcn_mfma_f32_16x16x32_bf16(af, w4f[s], acc2[m], 0, 0, 0);
        }
    }
    if (ccol < 10) {
        float* dst = sup4p + (size_t)(blockIdx.x * 2 + (w & 1)) * ((size_t)M * 10);
#pragma unroll
        for (int m = 0; m < 4; ++m)
#pragma unroll
            for (int r = 0; r < 4; ++r) {
                int gr = row0 + wr + m * 16 + crow + r;
                if (gr < M) dst[(size_t)gr * 10 + ccol] = acc2[m][r];
            }
    }
}

// ---------------- sum 32 partial slots -> sup4 ----------------
__global__ __launch_bounds__(256) void sup4_reduce(const float* __restrict__ P,
                                                   float* __restrict__ O, int n) {
    int i = blockIdx.x * 256 + threadIdx.x;
    if (i >= n) return;
    float s = 0.f;
#pragma unroll
    for (int j = 0; j < 32; ++j) s += P[(size_t)j * n + i];
    O[i] = s;
}

// ---------------- conversions ----------------
__global__ __launch_bounds__(256) void cvt4(const float* __restrict__ s,
                                            ushort* __restrict__ d, long n4) {
    long i = (long)blockIdx.x * 256 + threadIdx.x;
    if (i >= n4) return;
    float4 v = ((const float4*)s)[i];
    ushort4 o = { f2bf(v.x), f2bf(v.y), f2bf(v.z), f2bf(v.w) };
    ((ushort4*)d)[i] = o;
}

// Wt[n][k] (Npad x 512) = bf16(W[k][n]), zero-padded
__global__ __launch_bounds__(256) void cvt_wt(const float* __restrict__ W,
                                              ushort* __restrict__ Wt,
                                              int Ksrc, int Nsrc, int Npad) {
    int i = blockIdx.x * 256 + threadIdx.x;
    if (i >= Npad * 512) return;
    int n = i >> 9, k = i & 511;
    float v = (k < Ksrc && n < Nsrc) ? W[(size_t)k * Nsrc + n] : 0.f;
    Wt[i] = f2bf(v);
}

// ---------------- CSR build: count / scan / fill ----------------
__global__ __launch_bounds__(256) void csr_count(const int* __restrict__ rows,
                                                 int* __restrict__ cnt, int E) {
    int e = blockIdx.x * 256 + threadIdx.x;
    if (e < E) atomicAdd(&cnt[rows[e]], 1);
}

__global__ __launch_bounds__(256) void scan1(const int* __restrict__ cnt,
                                             int* __restrict__ csum, int n) {
    __shared__ int red[256];
    int base = blockIdx.x * SCAN_CHUNK;
    int t = threadIdx.x;
    int s = 0;
    if (base + t < n) s += cnt[base + t];
    if (base + t + 256 < n) s += cnt[base + t + 256];
    red[t] = s;
    __syncthreads();
    for (int off = 128; off; off >>= 1) {
        if (t < off) red[t] += red[t + off];
        __syncthreads();
    }
    if (t == 0) csum[blockIdx.x] = red[0];
}

__global__ void scan2(int* csum, int nch) {
    if (threadIdx.x == 0 && blockIdx.x == 0) {
        int acc = 0;
        for (int i = 0; i < nch; ++i) { int v = csum[i]; csum[i] = acc; acc += v; }
    }
}

__global__ __launch_bounds__(256) void scan3(const int* __restrict__ cnt,
                                             const int* __restrict__ csum,
                                             int* __restrict__ rowptr, int n, int E) {
    __shared__ int sm[SCAN_CHUNK];
    int base = blockIdx.x * SCAN_CHUNK;
    int t = threadIdx.x;
    for (int i = t; i < SCAN_CHUNK; i += 256) sm[i] = (base + i < n) ? cnt[base + i] : 0;
    __syncthreads();
    for (int off = 1; off < SCAN_CHUNK; off <<= 1) {
        int i0 = t, i1 = t + 256;
        int v0 = (i0 >= off) ? sm[i0 - off] : 0;
        int v1 = (i1 >= off) ? sm[i1 - off] : 0;
        __syncthreads();
        sm[i0] += v0;
        sm[i1] += v1;
        __syncthreads();
    }
    int off0 = csum[blockIdx.x];
    for (int i = t; i < SCAN_CHUNK; i += 256)
        if (base + i < n) rowptr[base + i] = off0 + (i ? sm[i - 1] : 0);
    if (blockIdx.x == 0 && t == 0) rowptr[n] = E;
}

__global__ __launch_bounds__(256) void csr_fill(const int* __restrict__ rows,
                                                const int* __restrict__ cols,
                                                const float* __restrict__ vals,
                                                int* __restrict__ cur,
                                                int2* __restrict__ edges, int E) {
    int e = blockIdx.x * 256 + threadIdx.x;
    if (e >= E) return;
    int p = atomicAdd(&cur[rows[e]], 1);
    edges[p] = make_int2(cols[e], __float_as_int(vals[e]));
}

// ---------------- SpMM gather, bf16 source [nrows,512]: wave per row ----------------
__global__ __launch_bounds__(256) void spmm_bf(const int* __restrict__ rowptr,
                                               const int2* __restrict__ edges,
                                               const ushort* __restrict__ S,
                                               const float* __restrict__ T,
                                               ushort* __restrict__ O,
                                               int nrows, int domix) {
    int wid = (int)((blockIdx.x * 256 + threadIdx.x) >> 6);
    int lane = threadIdx.x & 63;
    if (wid >= nrows) return;
    int beg = rowptr[wid], end = rowptr[wid + 1];
    float acc[8] = {0.f, 0.f, 0.f, 0.f, 0.f, 0.f, 0.f, 0.f};
    int e = beg;
    for (; e + 1 < end; e += 2) {
        int2 e0 = edges[e], e1 = edges[e + 1];
        float va = __int_as_float(e0.y), vb = __int_as_float(e1.y);
        s16x8 a = ((const s16x8*)(S + (size_t)e0.x * 512))[lane];
        s16x8 b = ((const s16x8*)(S + (size_t)e1.x * 512))[lane];
#pragma unroll
        for (int j = 0; j < 8; ++j)
            acc[j] += va * bf2f((ushort)a[j]) + vb * bf2f((ushort)b[j]);
    }
    if (e < end) {
        int2 e0 = edges[e];
        float va = __int_as_float(e0.y);
        s16x8 a = ((const s16x8*)(S + (size_t)e0.x * 512))[lane];
#pragma unroll
        for (int j = 0; j < 8; ++j)
            acc[j] += va * bf2f((ushort)a[j]);
    }
    int c0 = lane * 8;
    float res[8];
    if (domix) {
        float tv[8] = {0.f, 0.f, 0.f, 0.f, 0.f, 0.f, 0.f, 0.f};
        const float* trow = T + (size_t)wid * 500;
        if (c0 + 8 <= 500) {
            float4 t0 = *(const float4*)(trow + c0);
            float4 t1 = *(const float4*)(trow + c0 + 4);
            tv[0] = t0.x; tv[1] = t0.y; tv[2] = t0.z; tv[3] = t0.w;
            tv[4] = t1.x; tv[5] = t1.y; tv[6] = t1.z; tv[7] = t1.w;
        } else {
#pragma unroll
            for (int j = 0; j < 8; ++j)
                if (c0 + j < 500) tv[j] = trow[c0 + j];
        }
#pragma unroll
        for (int j = 0; j < 8; ++j)
            res[j] = (c0 + j < 500) ? (0.5f * fmaxf(acc[j], 0.f) + 0.5f * tv[j]) : 0.f;
    } else {
#pragma unroll
        for (int j = 0; j < 8; ++j)
            res[j] = (c0 + j < 500) ? acc[j] : 0.f;
    }
    s16x8 o;
#pragma unroll
    for (int j = 0; j < 8; ++j) o[j] = (short)f2bf(res[j]);
    ((s16x8*)(O + (size_t)wid * 512))[lane] = o;
}

// ---------------- SpMM gather, D=10 f32; optional fused mix+@W5 epilogue -------------
__global__ __launch_bounds__(256) void spmm10(const int* __restrict__ rowptr,
                                              const int2* __restrict__ edges,
                                              const float* __restrict__ S,
                                              const float* __restrict__ T,
                                              const float* __restrict__ W5,
                                              float* __restrict__ O, int nrows) {
    int g = (int)((blockIdx.x * 256 + threadIdx.x) >> 4);
    int t = threadIdx.x & 15;
    if (g >= nrows || t >= 10) return;
    int beg = rowptr[g], end = rowptr[g + 1];
    float acc = 0.f;
    for (int e = beg; e < end; ++e) {
        int2 ed = edges[e];
        acc += __int_as_float(ed.y) * S[(size_t)ed.x * 10 + t];
    }
    if (W5) {
        float m = 0.5f * fmaxf(acc, 0.f) + 0.5f * T[(size_t)g * 10 + t];
        float s5 = 0.f;
#pragma unroll
        for (int i = 0; i < 10; ++i)
            s5 += __shfl(m, i, 16) * W5[i * 10 + t];
        O[(size_t)g * 10 + t] = s5;
    } else {
        O[(size_t)g * 10 + t] = acc;
    }
}

extern "C" void kernel_launch(void* const* d_in, const int* in_sizes, int n_in,
                              void* d_out, int out_size, void* d_ws, size_t ws_size,
                              hipStream_t stream) {
    const float* x    = (const float*)d_in[0];
    const int*   ar   = (const int*)d_in[1];
    const int*   ac   = (const int*)d_in[2];
    const float* av   = (const float*)d_in[3];
    const float* tra1 = (const float*)d_in[4];
    const float* tra2 = (const float*)d_in[5];
    const float* tra3 = (const float*)d_in[6];
    const float* z    = (const float*)d_in[7];
    const float* W1   = (const float*)d_in[8];
    const float* W2   = (const float*)d_in[9];
    const float* W3   = (const float*)d_in[10];
    const float* W4   = (const float*)d_in[11];
    const float* W5   = (const float*)d_in[12];

    const int E = in_sizes[1];
    const int N = in_sizes[7] / 10;   // 50000
    const int NCH = (N + SCAN_CHUNK - 1) / SCAN_CHUNK;

    ushort* Abf    = (ushort*)d_ws;                     // [N,512] bf16
    ushort* Sbf    = Abf + (size_t)N * 512;             // [N,512] bf16
    ushort* Wt     = Sbf + (size_t)N * 512;             // [2048,512] bf16 (W1/W2/W3 in turn)
    float*  sup4   = (float*)(Wt + 2048 * 512);         // [N,10] f32
    float*  sup5   = sup4 + (size_t)N * 10;             // [N,10] f32
    float*  sup4p  = sup5 + (size_t)N * 10;             // [32][N*10] f32 partials (64 MB)
    int2*   edges  = (int2*)(sup4p + (size_t)32 * N * 10); // [E]
    int*    rowptr = (int*)(edges + E);                 // [N+1]
    int*    cnt    = rowptr + (N + 1);                  // [N]
    int*    csum   = cnt + N;                           // [NCH]
    float*  out    = (float*)d_out;

    dim3 blk(256);

    // ---- CSR build ----
    hipMemsetAsync(cnt, 0, (size_t)N * sizeof(int), stream);
    csr_count<<<(E + 255) / 256, blk, 0, stream>>>(ar, cnt, E);
    scan1<<<NCH, blk, 0, stream>>>(cnt, csum, N);
    scan2<<<1, 64, 0, stream>>>(csum, NCH);
    scan3<<<NCH, blk, 0, stream>>>(cnt, csum, rowptr, N, E);
    hipMemcpyAsync(cnt, rowptr, (size_t)N * sizeof(int), hipMemcpyDeviceToDevice, stream);
    csr_fill<<<(E + 255) / 256, blk, 0, stream>>>(ar, ac, av, cnt, edges, E);

    const int spmm_blocks   = (N * 64 + 255) / 256;
    const int spmm10_blocks = (N * 16 + 255) / 256;

    // ---- Layer 1: Abf = bf16(x); Sbf = Abf@W1t; Abf = mix(spmm(Sbf), tra1)
    cvt4<<<(int)(((long)N * 512 / 4 + 255) / 256), blk, 0, stream>>>(x, Abf, (long)N * 512 / 4);
    cvt_wt<<<(512 * 512 + 255) / 256, blk, 0, stream>>>(W1, Wt, 512, 500, 512);
    {
        dim3 g(4, (N + BM - 1) / BM);
        gemm_sup<<<g, blk, 0, stream>>>(Abf, Wt, Sbf, N);
    }
    spmm_bf<<<spmm_blocks, blk, 0, stream>>>(rowptr, edges, Sbf, tra1, Abf, N, 1);

    // ---- Layer 2: Sbf = Abf@W2t; Abf(m2) = mix(spmm(Sbf), tra2)
    cvt_wt<<<(512 * 512 + 255) / 256, blk, 0, stream>>>(W2, Wt, 500, 500, 512);
    {
        dim3 g(4, (N + BM - 1) / BM);
        gemm_sup<<<g, blk, 0, stream>>>(Abf, Wt, Sbf, N);
    }
    spmm_bf<<<spmm_blocks, blk, 0, stream>>>(rowptr, edges, Sbf, tra2, Abf, N, 1);

    // ---- Layer 3 (spmm-first, fused): Sbf(g) = spmm(m2) raw;
    //      sup4p = per-(colblock,wchalf) partials of mix(relu(g@W3), tra3) @ W4;
    //      sup4 = sum of 32 partials
    spmm_bf<<<spmm_blocks, blk, 0, stream>>>(rowptr, edges, Abf, nullptr, Sbf, N, 0);
    cvt_wt<<<(2048 * 512 + 255) / 256, blk, 0, stream>>>(W3, Wt, 500, 2000, 2048);
    {
        dim3 g(16, (N + BM - 1) / BM);
        gemm3_w4<<<g, blk, 0, stream>>>(Sbf, Wt, tra3, W4, sup4p, N);
    }
    sup4_reduce<<<(N * 10 + 255) / 256, blk, 0, stream>>>(sup4p, sup4, N * 10);

    // ---- Layer 4+5a: sup5 = (mix(spmm(sup4), z)) @ W5  (fused epilogue)
    spmm10<<<spmm10_blocks, blk, 0, stream>>>(rowptr, edges, sup4, z, W5, sup5, N);

    // ---- Layer 5b: out = spmm(sup5) raw
    spmm10<<<spmm10_blocks, blk, 0, stream>>>(rowptr, edges, sup5, nullptr, nullptr, out, N);
}

// Round 8
// 1444.612 us; speedup vs baseline: 1.1200x; 1.1200x over previous
//
#include <hip/hip_runtime.h>
#include <hip/hip_bf16.h>

// GNN: 5-layer GCN on MI355X. Round 8: latency attack on gemm3_w4 (was 493us with
// every pipe <=20% busy => latency-bound, occupancy 2 blocks/CU).
// 1) 2-phase double-buffered K-loop (issue next global_load_lds BEFORE compute) in
//    both MFMA GEMMs; LDS 64KB (2 blocks/CU unchanged - reg-capped anyway).
// 2) mix distributed through W4: sup4 = (relu(g@W3) + tra3) @ (0.5*W4).
//    tra3 tile now loaded COALESCED (float4) into the swizzled act-LDS and run
//    through a second stage-2 MFMA pass, replacing 64 scattered scalar loads/thread.
// Unchanged: XOR-swizzled LDS (r6), private partials + reduce (r7), CSR-gather SpMM.

#define SCAN_CHUNK 512
#define BM 128
#define BN 128
#define BK 64

typedef __attribute__((ext_vector_type(4))) float f32x4;
typedef __attribute__((ext_vector_type(8))) __bf16 bf16x8;
typedef __attribute__((ext_vector_type(8))) short s16x8;

__device__ __forceinline__ bf16x8 as_bf(s16x8 v) { union { s16x8 s; bf16x8 b; } u; u.s = v; return u.b; }
__device__ __forceinline__ ushort f2bf(float f) {
    uint u = __float_as_uint(f);
    return (ushort)((u + 0x7FFFu + ((u >> 16) & 1u)) >> 16);   // RNE
}
__device__ __forceinline__ float bf2f(ushort s) { return __uint_as_float(((uint)s) << 16); }

#define GLL16(g, l)                                                                 \
    __builtin_amdgcn_global_load_lds((const __attribute__((address_space(1))) void*)(g), \
                                     (__attribute__((address_space(3))) void*)(l), 16, 0, 0)

// stage one BK-slab of A and Bt into lds[base .. base+16384)
#define STAGE_TILE(k0, base)                                                        \
    _Pragma("unroll")                                                               \
    for (int i = 0; i < 4; ++i) {                                                   \
        int ar = row0 + arow_off + i * 32;                                          \
        if (ar >= M) ar = M - 1;                                                    \
        GLL16(A + (size_t)ar * 512 + (k0) + acol, &lds[(base) + (w * 8 + i * 32) * BK]); \
        GLL16(Bt + (size_t)(col0 + arow_off + i * 32) * 512 + (k0) + acol,          \
              &lds[(base) + 8192 + (w * 8 + i * 32) * BK]);                         \
    }

#define COMPUTE_TILE(base)                                                          \
    _Pragma("unroll")                                                               \
    for (int s = 0; s < 2; ++s) {                                                   \
        int cswz = (((s * 4 + (l >> 4)) ^ (l & 7)) << 3);                           \
        bf16x8 af[4], bfr[4];                                                       \
        _Pragma("unroll")                                                           \
        for (int m = 0; m < 4; ++m)                                                 \
            af[m] = as_bf(*(const s16x8*)&lds[(base) + (wr + m * 16 + (l & 15)) * BK + cswz]); \
        _Pragma("unroll")                                                           \
        for (int n = 0; n < 4; ++n)                                                 \
            bfr[n] = as_bf(*(const s16x8*)&lds[(base) + 8192 + (wc + n * 16 + (l & 15)) * BK + cswz]); \
        _Pragma("unroll")                                                           \
        for (int m = 0; m < 4; ++m)                                                 \
            _Pragma("unroll")                                                       \
            for (int n = 0; n < 4; ++n)                                             \
                acc[m][n] = __builtin_amdgcn_mfma_f32_16x16x32_bf16(af[m], bfr[n], acc[m][n], 0, 0, 0); \
    }

// ---------------- support GEMM: C[M,512]bf16 = A[M,512]bf16 @ Bt[512,512]bf16^T ------
__global__ __launch_bounds__(256) void gemm_sup(const ushort* __restrict__ A,
                                                const ushort* __restrict__ Bt,
                                                ushort* __restrict__ C, int M) {
    __shared__ ushort lds[32768];   // 64 KB: double-buffered As/Bs
    int tid = threadIdx.x;
    int w = tid >> 6, l = tid & 63;
    int row0 = blockIdx.y * BM, col0 = blockIdx.x * BN;
    int wr = (w >> 1) * 64, wc = (w & 1) * 64;
    f32x4 acc[4][4] = {};
    int arow_off = w * 8 + (l >> 3);
    int acol = (((l & 7) ^ (l >> 3)) << 3);   // swizzled global source chunk

    STAGE_TILE(0, 0);
    __syncthreads();
    int base = 0;
    for (int t = 0; t < 8; ++t) {
        if (t < 7) { STAGE_TILE((t + 1) * BK, base ^ 16384); }
        COMPUTE_TILE(base);
        __syncthreads();
        base ^= 16384;
    }

    int crow = (l >> 4) * 4, ccol = l & 15;
#pragma unroll
    for (int m = 0; m < 4; ++m)
#pragma unroll
        for (int n = 0; n < 4; ++n) {
            int gc = col0 + wc + n * 16 + ccol;
#pragma unroll
            for (int r = 0; r < 4; ++r) {
                int gr = row0 + wr + m * 16 + crow + r;
                if (gr < M) C[(size_t)gr * 512 + gc] = f2bf(acc[m][n][r]);
            }
        }
}

// ---------------- fused layer-3: partial = (relu(g@W3) + tra3) @ (0.5*W4) ------------
// A: g [M,512] bf16. Bt: Wt3 [2048,512] bf16 (pad rows zero). T: tra3 [M,2000] f32.
// W4: [2000,10] f32 (0.5 folded into reg B-frag). sup4p: [32][M*10] f32 partial slots.
__global__ __launch_bounds__(256) void gemm3_w4(const ushort* __restrict__ A,
                                                const ushort* __restrict__ Bt,
                                                const float* __restrict__ T,
                                                const float* __restrict__ W4,
                                                float* __restrict__ sup4p, int M) {
    __shared__ ushort lds[32768];   // 64 KB dbuf; epilogue act tile overlays [0:16384)
    int tid = threadIdx.x;
    int w = tid >> 6, l = tid & 63;
    int row0 = blockIdx.y * BM, col0 = blockIdx.x * BN;
    int wr = (w >> 1) * 64, wc = (w & 1) * 64;
    int crow = (l >> 4) * 4, ccol = l & 15;

    // B-fragment of 0.5*W4 in registers: lane holds cols=ccol, k=col0+wc+s*32+(l>>4)*8+kk
    bf16x8 w4f[2];
#pragma unroll
    for (int s = 0; s < 2; ++s) {
        s16x8 tmp;
#pragma unroll
        for (int kk = 0; kk < 8; ++kk) {
            int gk = col0 + wc + s * 32 + ((l >> 4) << 3) + kk;
            float v = (ccol < 10 && gk < 2000) ? 0.5f * W4[(size_t)gk * 10 + ccol] : 0.f;
            tmp[kk] = (short)f2bf(v);
        }
        w4f[s] = as_bf(tmp);
    }

    f32x4 acc[4][4] = {};
    int arow_off = w * 8 + (l >> 3);
    int acol = (((l & 7) ^ (l >> 3)) << 3);

    STAGE_TILE(0, 0);
    __syncthreads();
    int base = 0;
    for (int t = 0; t < 8; ++t) {
        if (t < 7) { STAGE_TILE((t + 1) * BK, base ^ 16384); }
        COMPUTE_TILE(base);
        __syncthreads();
        base ^= 16384;
    }

    ushort* actS = lds;   // [128][128] swizzled, overlays buffer 0

    // ---- epilogue A: relu(acc) -> actS (fragment writes, swizzled)
#pragma unroll
    for (int m = 0; m < 4; ++m)
#pragma unroll
        for (int n = 0; n < 4; ++n) {
            int cl = wc + n * 16 + ccol;
            int cch = cl >> 3, clo = cl & 7;
#pragma unroll
            for (int r = 0; r < 4; ++r) {
                int rl = wr + m * 16 + crow + r;
                actS[rl * 128 + (((cch ^ (rl & 7)) << 3) | clo)] = f2bf(fmaxf(acc[m][n][r], 0.f));
            }
        }
    __syncthreads();

    // ---- stage-2a: relu-part @ 0.5W4
    f32x4 acc2[4] = {};
#pragma unroll
    for (int s = 0; s < 2; ++s) {
        int chunk = (wc + s * 32 + ((l >> 4) << 3)) >> 3;
#pragma unroll
        for (int m = 0; m < 4; ++m) {
            int row = wr + m * 16 + ccol;
            bf16x8 af = as_bf(*(const s16x8*)&actS[row * 128 + ((chunk ^ (row & 7)) << 3)]);
            acc2[m] = __builtin_amdgcn_mfma_f32_16x16x32_bf16(af, w4f[s], acc2[m], 0, 0, 0);
        }
    }
    __syncthreads();   // done reading relu tile

    // ---- epilogue B: tra3 tile -> actS, COALESCED (lanes 0-31 read 512 contiguous B)
    {
        int r_off = tid >> 5;            // 0..7
        int c4 = (tid & 31) * 4;         // col within tile, multiple of 4
        int chunk = (tid & 31) >> 1;
        int lo = (tid & 1) * 4;
#pragma unroll
        for (int p = 0; p < 16; ++p) {
            int rl = p * 8 + r_off;
            int gr = row0 + rl;
            int gcb = col0 + c4;
            ushort4 h;
            if (gr < M && gcb + 3 < 2000) {
                float4 tv = *(const float4*)(T + (size_t)gr * 2000 + gcb);
                h.x = f2bf(tv.x); h.y = f2bf(tv.y); h.z = f2bf(tv.z); h.w = f2bf(tv.w);
            } else {
                float e[4];
#pragma unroll
                for (int i = 0; i < 4; ++i)
                    e[i] = (gr < M && gcb + i < 2000) ? T[(size_t)gr * 2000 + gcb + i] : 0.f;
                h.x = f2bf(e[0]); h.y = f2bf(e[1]); h.z = f2bf(e[2]); h.w = f2bf(e[3]);
            }
            *(ushort4*)&actS[rl * 128 + ((chunk ^ (rl & 7)) << 3) + lo] = h;
        }
    }
    __syncthreads();

    // ---- stage-2b: tra3-part @ 0.5W4 (accumulate into acc2)
#pragma unroll
    for (int s = 0; s < 2; ++s) {
        int chunk = (wc + s * 32 + ((l >> 4) << 3)) >> 3;
#pragma unroll
        for (int m = 0; m < 4; ++m) {
            int row = wr + m * 16 + ccol;
            bf16x8 af = as_bf(*(const s16x8*)&actS[row * 128 + ((chunk ^ (row & 7)) << 3)]);
            acc2[m] = __builtin_amdgcn_mfma_f32_16x16x32_bf16(af, w4f[s], acc2[m], 0, 0, 0);
        }
    }

    if (ccol < 10) {
        float* dst = sup4p + (size_t)(blockIdx.x * 2 + (w & 1)) * ((size_t)M * 10);
#pragma unroll
        for (int m = 0; m < 4; ++m)
#pragma unroll
            for (int r = 0; r < 4; ++r) {
                int gr = row0 + wr + m * 16 + crow + r;
                if (gr < M) dst[(size_t)gr * 10 + ccol] = acc2[m][r];
            }
    }
}

// ---------------- sum 32 partial slots -> sup4 ----------------
__global__ __launch_bounds__(256) void sup4_reduce(const float* __restrict__ P,
                                                   float* __restrict__ O, int n) {
    int i = blockIdx.x * 256 + threadIdx.x;
    if (i >= n) return;
    float s = 0.f;
#pragma unroll
    for (int j = 0; j < 32; ++j) s += P[(size_t)j * n + i];
    O[i] = s;
}

// ---------------- conversions ----------------
__global__ __launch_bounds__(256) void cvt4(const float* __restrict__ s,
                                            ushort* __restrict__ d, long n4) {
    long i = (long)blockIdx.x * 256 + threadIdx.x;
    if (i >= n4) return;
    float4 v = ((const float4*)s)[i];
    ushort4 o = { f2bf(v.x), f2bf(v.y), f2bf(v.z), f2bf(v.w) };
    ((ushort4*)d)[i] = o;
}

// Wt[n][k] (Npad x 512) = bf16(W[k][n]), zero-padded
__global__ __launch_bounds__(256) void cvt_wt(const float* __restrict__ W,
                                              ushort* __restrict__ Wt,
                                              int Ksrc, int Nsrc, int Npad) {
    int i = blockIdx.x * 256 + threadIdx.x;
    if (i >= Npad * 512) return;
    int n = i >> 9, k = i & 511;
    float v = (k < Ksrc && n < Nsrc) ? W[(size_t)k * Nsrc + n] : 0.f;
    Wt[i] = f2bf(v);
}

// ---------------- CSR build: count / scan / fill ----------------
__global__ __launch_bounds__(256) void csr_count(const int* __restrict__ rows,
                                                 int* __restrict__ cnt, int E) {
    int e = blockIdx.x * 256 + threadIdx.x;
    if (e < E) atomicAdd(&cnt[rows[e]], 1);
}

__global__ __launch_bounds__(256) void scan1(const int* __restrict__ cnt,
                                             int* __restrict__ csum, int n) {
    __shared__ int red[256];
    int base = blockIdx.x * SCAN_CHUNK;
    int t = threadIdx.x;
    int s = 0;
    if (base + t < n) s += cnt[base + t];
    if (base + t + 256 < n) s += cnt[base + t + 256];
    red[t] = s;
    __syncthreads();
    for (int off = 128; off; off >>= 1) {
        if (t < off) red[t] += red[t + off];
        __syncthreads();
    }
    if (t == 0) csum[blockIdx.x] = red[0];
}

__global__ void scan2(int* csum, int nch) {
    if (threadIdx.x == 0 && blockIdx.x == 0) {
        int acc = 0;
        for (int i = 0; i < nch; ++i) { int v = csum[i]; csum[i] = acc; acc += v; }
    }
}

__global__ __launch_bounds__(256) void scan3(const int* __restrict__ cnt,
                                             const int* __restrict__ csum,
                                             int* __restrict__ rowptr, int n, int E) {
    __shared__ int sm[SCAN_CHUNK];
    int base = blockIdx.x * SCAN_CHUNK;
    int t = threadIdx.x;
    for (int i = t; i < SCAN_CHUNK; i += 256) sm[i] = (base + i < n) ? cnt[base + i] : 0;
    __syncthreads();
    for (int off = 1; off < SCAN_CHUNK; off <<= 1) {
        int i0 = t, i1 = t + 256;
        int v0 = (i0 >= off) ? sm[i0 - off] : 0;
        int v1 = (i1 >= off) ? sm[i1 - off] : 0;
        __syncthreads();
        sm[i0] += v0;
        sm[i1] += v1;
        __syncthreads();
    }
    int off0 = csum[blockIdx.x];
    for (int i = t; i < SCAN_CHUNK; i += 256)
        if (base + i < n) rowptr[base + i] = off0 + (i ? sm[i - 1] : 0);
    if (blockIdx.x == 0 && t == 0) rowptr[n] = E;
}

__global__ __launch_bounds__(256) void csr_fill(const int* __restrict__ rows,
                                                const int* __restrict__ cols,
                                                const float* __restrict__ vals,
                                                int* __restrict__ cur,
                                                int2* __restrict__ edges, int E) {
    int e = blockIdx.x * 256 + threadIdx.x;
    if (e >= E) return;
    int p = atomicAdd(&cur[rows[e]], 1);
    edges[p] = make_int2(cols[e], __float_as_int(vals[e]));
}

// ---------------- SpMM gather, bf16 source [nrows,512]: wave per row ----------------
__global__ __launch_bounds__(256) void spmm_bf(const int* __restrict__ rowptr,
                                               const int2* __restrict__ edges,
                                               const ushort* __restrict__ S,
                                               const float* __restrict__ T,
                                               ushort* __restrict__ O,
                                               int nrows, int domix) {
    int wid = (int)((blockIdx.x * 256 + threadIdx.x) >> 6);
    int lane = threadIdx.x & 63;
    if (wid >= nrows) return;
    int beg = rowptr[wid], end = rowptr[wid + 1];
    float acc[8] = {0.f, 0.f, 0.f, 0.f, 0.f, 0.f, 0.f, 0.f};
    int e = beg;
    for (; e + 1 < end; e += 2) {
        int2 e0 = edges[e], e1 = edges[e + 1];
        float va = __int_as_float(e0.y), vb = __int_as_float(e1.y);
        s16x8 a = ((const s16x8*)(S + (size_t)e0.x * 512))[lane];
        s16x8 b = ((const s16x8*)(S + (size_t)e1.x * 512))[lane];
#pragma unroll
        for (int j = 0; j < 8; ++j)
            acc[j] += va * bf2f((ushort)a[j]) + vb * bf2f((ushort)b[j]);
    }
    if (e < end) {
        int2 e0 = edges[e];
        float va = __int_as_float(e0.y);
        s16x8 a = ((const s16x8*)(S + (size_t)e0.x * 512))[lane];
#pragma unroll
        for (int j = 0; j < 8; ++j)
            acc[j] += va * bf2f((ushort)a[j]);
    }
    int c0 = lane * 8;
    float res[8];
    if (domix) {
        float tv[8] = {0.f, 0.f, 0.f, 0.f, 0.f, 0.f, 0.f, 0.f};
        const float* trow = T + (size_t)wid * 500;
        if (c0 + 8 <= 500) {
            float4 t0 = *(const float4*)(trow + c0);
            float4 t1 = *(const float4*)(trow + c0 + 4);
            tv[0] = t0.x; tv[1] = t0.y; tv[2] = t0.z; tv[3] = t0.w;
            tv[4] = t1.x; tv[5] = t1.y; tv[6] = t1.z; tv[7] = t1.w;
        } else {
#pragma unroll
            for (int j = 0; j < 8; ++j)
                if (c0 + j < 500) tv[j] = trow[c0 + j];
        }
#pragma unroll
        for (int j = 0; j < 8; ++j)
            res[j] = (c0 + j < 500) ? (0.5f * fmaxf(acc[j], 0.f) + 0.5f * tv[j]) : 0.f;
    } else {
#pragma unroll
        for (int j = 0; j < 8; ++j)
            res[j] = (c0 + j < 500) ? acc[j] : 0.f;
    }
    s16x8 o;
#pragma unroll
    for (int j = 0; j < 8; ++j) o[j] = (short)f2bf(res[j]);
    ((s16x8*)(O + (size_t)wid * 512))[lane] = o;
}

// ---------------- SpMM gather, D=10 f32; optional fused mix+@W5 epilogue -------------
__global__ __launch_bounds__(256) void spmm10(const int* __restrict__ rowptr,
                                              const int2* __restrict__ edges,
                                              const float* __restrict__ S,
                                              const float* __restrict__ T,
                                              const float* __restrict__ W5,
                                              float* __restrict__ O, int nrows) {
    int g = (int)((blockIdx.x * 256 + threadIdx.x) >> 4);
    int t = threadIdx.x & 15;
    if (g >= nrows || t >= 10) return;
    int beg = rowptr[g], end = rowptr[g + 1];
    float acc = 0.f;
    for (int e = beg; e < end; ++e) {
        int2 ed = edges[e];
        acc += __int_as_float(ed.y) * S[(size_t)ed.x * 10 + t];
    }
    if (W5) {
        float m = 0.5f * fmaxf(acc, 0.f) + 0.5f * T[(size_t)g * 10 + t];
        float s5 = 0.f;
#pragma unroll
        for (int i = 0; i < 10; ++i)
            s5 += __shfl(m, i, 16) * W5[i * 10 + t];
        O[(size_t)g * 10 + t] = s5;
    } else {
        O[(size_t)g * 10 + t] = acc;
    }
}

extern "C" void kernel_launch(void* const* d_in, const int* in_sizes, int n_in,
                              void* d_out, int out_size, void* d_ws, size_t ws_size,
                              hipStream_t stream) {
    const float* x    = (const float*)d_in[0];
    const int*   ar   = (const int*)d_in[1];
    const int*   ac   = (const int*)d_in[2];
    const float* av   = (const float*)d_in[3];
    const float* tra1 = (const float*)d_in[4];
    const float* tra2 = (const float*)d_in[5];
    const float* tra3 = (const float*)d_in[6];
    const float* z    = (const float*)d_in[7];
    const float* W1   = (const float*)d_in[8];
    const float* W2   = (const float*)d_in[9];
    const float* W3   = (const float*)d_in[10];
    const float* W4   = (const float*)d_in[11];
    const float* W5   = (const float*)d_in[12];

    const int E = in_sizes[1];
    const int N = in_sizes[7] / 10;   // 50000
    const int NCH = (N + SCAN_CHUNK - 1) / SCAN_CHUNK;

    ushort* Abf    = (ushort*)d_ws;                     // [N,512] bf16
    ushort* Sbf    = Abf + (size_t)N * 512;             // [N,512] bf16
    ushort* Wt     = Sbf + (size_t)N * 512;             // [2048,512] bf16 (W1/W2/W3 in turn)
    float*  sup4   = (float*)(Wt + 2048 * 512);         // [N,10] f32
    float*  sup5   = sup4 + (size_t)N * 10;             // [N,10] f32
    float*  sup4p  = sup5 + (size_t)N * 10;             // [32][N*10] f32 partials (64 MB)
    int2*   edges  = (int2*)(sup4p + (size_t)32 * N * 10); // [E]
    int*    rowptr = (int*)(edges + E);                 // [N+1]
    int*    cnt    = rowptr + (N + 1);                  // [N]
    int*    csum   = cnt + N;                           // [NCH]
    float*  out    = (float*)d_out;

    dim3 blk(256);

    // ---- CSR build ----
    hipMemsetAsync(cnt, 0, (size_t)N * sizeof(int), stream);
    csr_count<<<(E + 255) / 256, blk, 0, stream>>>(ar, cnt, E);
    scan1<<<NCH, blk, 0, stream>>>(cnt, csum, N);
    scan2<<<1, 64, 0, stream>>>(csum, NCH);
    scan3<<<NCH, blk, 0, stream>>>(cnt, csum, rowptr, N, E);
    hipMemcpyAsync(cnt, rowptr, (size_t)N * sizeof(int), hipMemcpyDeviceToDevice, stream);
    csr_fill<<<(E + 255) / 256, blk, 0, stream>>>(ar, ac, av, cnt, edges, E);

    const int spmm_blocks   = (N * 64 + 255) / 256;
    const int spmm10_blocks = (N * 16 + 255) / 256;

    // ---- Layer 1: Abf = bf16(x); Sbf = Abf@W1t; Abf = mix(spmm(Sbf), tra1)
    cvt4<<<(int)(((long)N * 512 / 4 + 255) / 256), blk, 0, stream>>>(x, Abf, (long)N * 512 / 4);
    cvt_wt<<<(512 * 512 + 255) / 256, blk, 0, stream>>>(W1, Wt, 512, 500, 512);
    {
        dim3 g(4, (N + BM - 1) / BM);
        gemm_sup<<<g, blk, 0, stream>>>(Abf, Wt, Sbf, N);
    }
    spmm_bf<<<spmm_blocks, blk, 0, stream>>>(rowptr, edges, Sbf, tra1, Abf, N, 1);

    // ---- Layer 2: Sbf = Abf@W2t; Abf(m2) = mix(spmm(Sbf), tra2)
    cvt_wt<<<(512 * 512 + 255) / 256, blk, 0, stream>>>(W2, Wt, 500, 500, 512);
    {
        dim3 g(4, (N + BM - 1) / BM);
        gemm_sup<<<g, blk, 0, stream>>>(Abf, Wt, Sbf, N);
    }
    spmm_bf<<<spmm_blocks, blk, 0, stream>>>(rowptr, edges, Sbf, tra2, Abf, N, 1);

    // ---- Layer 3 (spmm-first, fused): Sbf(g) = spmm(m2) raw;
    //      sup4p = per-(colblock,wchalf) partials of (relu(g@W3)+tra3)@(0.5*W4);
    //      sup4 = sum of 32 partials
    spmm_bf<<<spmm_blocks, blk, 0, stream>>>(rowptr, edges, Abf, nullptr, Sbf, N, 0);
    cvt_wt<<<(2048 * 512 + 255) / 256, blk, 0, stream>>>(W3, Wt, 500, 2000, 2048);
    {
        dim3 g(16, (N + BM - 1) / BM);
        gemm3_w4<<<g, blk, 0, stream>>>(Sbf, Wt, tra3, W4, sup4p, N);
    }
    sup4_reduce<<<(N * 10 + 255) / 256, blk, 0, stream>>>(sup4p, sup4, N * 10);

    // ---- Layer 4+5a: sup5 = (mix(spmm(sup4), z)) @ W5  (fused epilogue)
    spmm10<<<spmm10_blocks, blk, 0, stream>>>(rowptr, edges, sup4, z, W5, sup5, N);

    // ---- Layer 5b: out = spmm(sup5) raw
    spmm10<<<spmm10_blocks, blk, 0, stream>>>(rowptr, edges, sup5, nullptr, nullptr, out, N);
}

// Round 9
// 1421.195 us; speedup vs baseline: 1.1385x; 1.0165x over previous
//
#include <hip/hip_runtime.h>
#include <hip/hip_bf16.h>

// GNN: 5-layer GCN on MI355X. Round 9: occupancy attack.
// r8 left gemm3_w4/gemm_sup LDS-capped at 8 waves/CU (64KB/block, 256 thr): 2 blocks x
// 4 waves. Now 512-thread 8-wave blocks at the SAME 128x128 tile + 64KB dbuf LDS ->
// 2 blocks x 16 waves = 50% occupancy; per-wave acc shrinks 4x4->4x2.
// gemm3_w4 stage-2 splits K across the 4 wc-waves (64 partial slots, reduce sums 64).
// spmm_bf: 4-edge unroll (4 gathers in flight vs 2).
// Unchanged: XOR-swizzle (r6), mix-through-W4 (r8), 2-phase dbuf K-loop (r8), CSR gather.

#define SCAN_CHUNK 512
#define BM 128
#define BN 128
#define BK 64

typedef __attribute__((ext_vector_type(4))) float f32x4;
typedef __attribute__((ext_vector_type(8))) __bf16 bf16x8;
typedef __attribute__((ext_vector_type(8))) short s16x8;

__device__ __forceinline__ bf16x8 as_bf(s16x8 v) { union { s16x8 s; bf16x8 b; } u; u.s = v; return u.b; }
__device__ __forceinline__ ushort f2bf(float f) {
    uint u = __float_as_uint(f);
    return (ushort)((u + 0x7FFFu + ((u >> 16) & 1u)) >> 16);   // RNE
}
__device__ __forceinline__ float bf2f(ushort s) { return __uint_as_float(((uint)s) << 16); }

#define GLL16(g, l)                                                                 \
    __builtin_amdgcn_global_load_lds((const __attribute__((address_space(1))) void*)(g), \
                                     (__attribute__((address_space(3))) void*)(l), 16, 0, 0)

// 8-wave staging: wave w covers rows w*8..w*8+7 (+64 for i=1); lane l>>3 = row-in-group,
// l&7 = 16B chunk; global source column pre-swizzled (acol) so linear LDS dest + XOR read works.
#define STAGE_TILE8(k0, base)                                                       \
    _Pragma("unroll")                                                               \
    for (int i = 0; i < 2; ++i) {                                                   \
        int ar = row0 + arow_off + i * 64;                                          \
        if (ar >= M) ar = M - 1;                                                    \
        GLL16(A + (size_t)ar * 512 + (k0) + acol, &lds[(base) + (w * 8 + i * 64) * BK]); \
        GLL16(Bt + (size_t)(col0 + arow_off + i * 64) * 512 + (k0) + acol,          \
              &lds[(base) + 8192 + (w * 8 + i * 64) * BK]);                         \
    }

// wave w computes 64x32: wr=(w>>2)*64, wc=(w&3)*32; fragments 4(m) x 2(n)
#define COMPUTE_TILE8(base)                                                         \
    _Pragma("unroll")                                                               \
    for (int s = 0; s < 2; ++s) {                                                   \
        int cswz = (((s * 4 + (l >> 4)) ^ (l & 7)) << 3);                           \
        bf16x8 af[4], bfr[2];                                                       \
        _Pragma("unroll")                                                           \
        for (int m = 0; m < 4; ++m)                                                 \
            af[m] = as_bf(*(const s16x8*)&lds[(base) + (wr + m * 16 + (l & 15)) * BK + cswz]); \
        _Pragma("unroll")                                                           \
        for (int n = 0; n < 2; ++n)                                                 \
            bfr[n] = as_bf(*(const s16x8*)&lds[(base) + 8192 + (wc + n * 16 + (l & 15)) * BK + cswz]); \
        _Pragma("unroll")                                                           \
        for (int m = 0; m < 4; ++m)                                                 \
            _Pragma("unroll")                                                       \
            for (int n = 0; n < 2; ++n)                                             \
                acc[m][n] = __builtin_amdgcn_mfma_f32_16x16x32_bf16(af[m], bfr[n], acc[m][n], 0, 0, 0); \
    }

// ---------------- support GEMM: C[M,512]bf16 = A[M,512]bf16 @ Bt[512,512]bf16^T ------
__global__ __launch_bounds__(512) void gemm_sup(const ushort* __restrict__ A,
                                                const ushort* __restrict__ Bt,
                                                ushort* __restrict__ C, int M) {
    __shared__ ushort lds[32768];   // 64 KB: double-buffered As/Bs
    int tid = threadIdx.x;
    int w = tid >> 6, l = tid & 63;
    int row0 = blockIdx.y * BM, col0 = blockIdx.x * BN;
    int wr = (w >> 2) * 64, wc = (w & 3) * 32;
    f32x4 acc[4][2] = {};
    int arow_off = w * 8 + (l >> 3);
    int acol = (((l & 7) ^ (l >> 3)) << 3);

    STAGE_TILE8(0, 0);
    __syncthreads();
    int base = 0;
    for (int t = 0; t < 8; ++t) {
        if (t < 7) { STAGE_TILE8((t + 1) * BK, base ^ 16384); }
        COMPUTE_TILE8(base);
        __syncthreads();
        base ^= 16384;
    }

    int crow = (l >> 4) * 4, ccol = l & 15;
#pragma unroll
    for (int m = 0; m < 4; ++m)
#pragma unroll
        for (int n = 0; n < 2; ++n) {
            int gc = col0 + wc + n * 16 + ccol;
#pragma unroll
            for (int r = 0; r < 4; ++r) {
                int gr = row0 + wr + m * 16 + crow + r;
                if (gr < M) C[(size_t)gr * 512 + gc] = f2bf(acc[m][n][r]);
            }
        }
}

// ---------------- fused layer-3: partial = (relu(g@W3) + tra3) @ (0.5*W4) ------------
// 8 waves; stage-2 K (=128) split across the 4 wc-waves (32 each).
// sup4p slot = blockIdx.x*4 + (w&3)  (waves w and w+4 share a slot, disjoint rows).
__global__ __launch_bounds__(512) void gemm3_w4(const ushort* __restrict__ A,
                                                const ushort* __restrict__ Bt,
                                                const float* __restrict__ T,
                                                const float* __restrict__ W4,
                                                float* __restrict__ sup4p, int M) {
    __shared__ ushort lds[32768];   // 64 KB dbuf; epilogue act tile overlays [0:16384)
    int tid = threadIdx.x;
    int w = tid >> 6, l = tid & 63;
    int row0 = blockIdx.y * BM, col0 = blockIdx.x * BN;
    int wr = (w >> 2) * 64, wc = (w & 3) * 32;
    int crow = (l >> 4) * 4, ccol = l & 15;

    // B-frag of 0.5*W4 in registers; this wave's k-quarter: col0 + (w&3)*32 + (l>>4)*8 + kk
    bf16x8 w4f;
    {
        s16x8 tmp;
#pragma unroll
        for (int kk = 0; kk < 8; ++kk) {
            int gk = col0 + (w & 3) * 32 + ((l >> 4) << 3) + kk;
            float v = (ccol < 10 && gk < 2000) ? 0.5f * W4[(size_t)gk * 10 + ccol] : 0.f;
            tmp[kk] = (short)f2bf(v);
        }
        w4f = as_bf(tmp);
    }

    f32x4 acc[4][2] = {};
    int arow_off = w * 8 + (l >> 3);
    int acol = (((l & 7) ^ (l >> 3)) << 3);

    STAGE_TILE8(0, 0);
    __syncthreads();
    int base = 0;
    for (int t = 0; t < 8; ++t) {
        if (t < 7) { STAGE_TILE8((t + 1) * BK, base ^ 16384); }
        COMPUTE_TILE8(base);
        __syncthreads();
        base ^= 16384;
    }

    ushort* actS = lds;   // [128][128] swizzled, overlays buffer 0

    // ---- epilogue A: relu(acc) -> actS (fragment writes, swizzled)
#pragma unroll
    for (int m = 0; m < 4; ++m)
#pragma unroll
        for (int n = 0; n < 2; ++n) {
            int cl = wc + n * 16 + ccol;
            int cch = cl >> 3, clo = cl & 7;
#pragma unroll
            for (int r = 0; r < 4; ++r) {
                int rl = wr + m * 16 + crow + r;
                actS[rl * 128 + (((cch ^ (rl & 7)) << 3) | clo)] = f2bf(fmaxf(acc[m][n][r], 0.f));
            }
        }
    __syncthreads();

    // ---- stage-2a: relu-part @ 0.5W4 (this wave's 64 rows x its 32-k quarter)
    f32x4 acc2[4] = {};
    {
        int chunk = (w & 3) * 4 + (l >> 4);
#pragma unroll
        for (int m = 0; m < 4; ++m) {
            int row = wr + m * 16 + ccol;
            bf16x8 af = as_bf(*(const s16x8*)&actS[row * 128 + ((chunk ^ (row & 7)) << 3)]);
            acc2[m] = __builtin_amdgcn_mfma_f32_16x16x32_bf16(af, w4f, acc2[m], 0, 0, 0);
        }
    }
    __syncthreads();   // done reading relu tile

    // ---- epilogue B: tra3 tile -> actS, COALESCED (float4 per thread, 8 rounds)
    {
        int r_off = tid >> 5;            // 0..15
        int c4 = (tid & 31) * 4;
        int chunk = (tid & 31) >> 1;
        int lo = (tid & 1) * 4;
#pragma unroll
        for (int p = 0; p < 8; ++p) {
            int rl = p * 16 + r_off;
            int gr = row0 + rl;
            int gcb = col0 + c4;
            ushort4 h;
            if (gr < M && gcb + 3 < 2000) {
                float4 tv = *(const float4*)(T + (size_t)gr * 2000 + gcb);
                h.x = f2bf(tv.x); h.y = f2bf(tv.y); h.z = f2bf(tv.z); h.w = f2bf(tv.w);
            } else {
                float e[4];
#pragma unroll
                for (int i = 0; i < 4; ++i)
                    e[i] = (gr < M && gcb + i < 2000) ? T[(size_t)gr * 2000 + gcb + i] : 0.f;
                h.x = f2bf(e[0]); h.y = f2bf(e[1]); h.z = f2bf(e[2]); h.w = f2bf(e[3]);
            }
            *(ushort4*)&actS[rl * 128 + ((chunk ^ (rl & 7)) << 3) + lo] = h;
        }
    }
    __syncthreads();

    // ---- stage-2b: tra3-part @ 0.5W4 (accumulate into acc2)
    {
        int chunk = (w & 3) * 4 + (l >> 4);
#pragma unroll
        for (int m = 0; m < 4; ++m) {
            int row = wr + m * 16 + ccol;
            bf16x8 af = as_bf(*(const s16x8*)&actS[row * 128 + ((chunk ^ (row & 7)) << 3)]);
            acc2[m] = __builtin_amdgcn_mfma_f32_16x16x32_bf16(af, w4f, acc2[m], 0, 0, 0);
        }
    }

    if (ccol < 10) {
        float* dst = sup4p + (size_t)(blockIdx.x * 4 + (w & 3)) * ((size_t)M * 10);
#pragma unroll
        for (int m = 0; m < 4; ++m)
#pragma unroll
            for (int r = 0; r < 4; ++r) {
                int gr = row0 + wr + m * 16 + crow + r;
                if (gr < M) dst[(size_t)gr * 10 + ccol] = acc2[m][r];
            }
    }
}

// ---------------- sum 64 partial slots -> sup4 ----------------
__global__ __launch_bounds__(256) void sup4_reduce(const float* __restrict__ P,
                                                   float* __restrict__ O, int n) {
    int i = blockIdx.x * 256 + threadIdx.x;
    if (i >= n) return;
    float s = 0.f;
#pragma unroll
    for (int j = 0; j < 64; ++j) s += P[(size_t)j * n + i];
    O[i] = s;
}

// ---------------- conversions ----------------
__global__ __launch_bounds__(256) void cvt4(const float* __restrict__ s,
                                            ushort* __restrict__ d, long n4) {
    long i = (long)blockIdx.x * 256 + threadIdx.x;
    if (i >= n4) return;
    float4 v = ((const float4*)s)[i];
    ushort4 o = { f2bf(v.x), f2bf(v.y), f2bf(v.z), f2bf(v.w) };
    ((ushort4*)d)[i] = o;
}

// Wt[n][k] (Npad x 512) = bf16(W[k][n]), zero-padded
__global__ __launch_bounds__(256) void cvt_wt(const float* __restrict__ W,
                                              ushort* __restrict__ Wt,
                                              int Ksrc, int Nsrc, int Npad) {
    int i = blockIdx.x * 256 + threadIdx.x;
    if (i >= Npad * 512) return;
    int n = i >> 9, k = i & 511;
    float v = (k < Ksrc && n < Nsrc) ? W[(size_t)k * Nsrc + n] : 0.f;
    Wt[i] = f2bf(v);
}

// ---------------- CSR build: count / scan / fill ----------------
__global__ __launch_bounds__(256) void csr_count(const int* __restrict__ rows,
                                                 int* __restrict__ cnt, int E) {
    int e = blockIdx.x * 256 + threadIdx.x;
    if (e < E) atomicAdd(&cnt[rows[e]], 1);
}

__global__ __launch_bounds__(256) void scan1(const int* __restrict__ cnt,
                                             int* __restrict__ csum, int n) {
    __shared__ int red[256];
    int base = blockIdx.x * SCAN_CHUNK;
    int t = threadIdx.x;
    int s = 0;
    if (base + t < n) s += cnt[base + t];
    if (base + t + 256 < n) s += cnt[base + t + 256];
    red[t] = s;
    __syncthreads();
    for (int off = 128; off; off >>= 1) {
        if (t < off) red[t] += red[t + off];
        __syncthreads();
    }
    if (t == 0) csum[blockIdx.x] = red[0];
}

__global__ void scan2(int* csum, int nch) {
    if (threadIdx.x == 0 && blockIdx.x == 0) {
        int acc = 0;
        for (int i = 0; i < nch; ++i) { int v = csum[i]; csum[i] = acc; acc += v; }
    }
}

__global__ __launch_bounds__(256) void scan3(const int* __restrict__ cnt,
                                             const int* __restrict__ csum,
                                             int* __restrict__ rowptr, int n, int E) {
    __shared__ int sm[SCAN_CHUNK];
    int base = blockIdx.x * SCAN_CHUNK;
    int t = threadIdx.x;
    for (int i = t; i < SCAN_CHUNK; i += 256) sm[i] = (base + i < n) ? cnt[base + i] : 0;
    __syncthreads();
    for (int off = 1; off < SCAN_CHUNK; off <<= 1) {
        int i0 = t, i1 = t + 256;
        int v0 = (i0 >= off) ? sm[i0 - off] : 0;
        int v1 = (i1 >= off) ? sm[i1 - off] : 0;
        __syncthreads();
        sm[i0] += v0;
        sm[i1] += v1;
        __syncthreads();
    }
    int off0 = csum[blockIdx.x];
    for (int i = t; i < SCAN_CHUNK; i += 256)
        if (base + i < n) rowptr[base + i] = off0 + (i ? sm[i - 1] : 0);
    if (blockIdx.x == 0 && t == 0) rowptr[n] = E;
}

__global__ __launch_bounds__(256) void csr_fill(const int* __restrict__ rows,
                                                const int* __restrict__ cols,
                                                const float* __restrict__ vals,
                                                int* __restrict__ cur,
                                                int2* __restrict__ edges, int E) {
    int e = blockIdx.x * 256 + threadIdx.x;
    if (e >= E) return;
    int p = atomicAdd(&cur[rows[e]], 1);
    edges[p] = make_int2(cols[e], __float_as_int(vals[e]));
}

// ---------------- SpMM gather, bf16 source [nrows,512]: wave per row, 4-edge unroll --
__global__ __launch_bounds__(256) void spmm_bf(const int* __restrict__ rowptr,
                                               const int2* __restrict__ edges,
                                               const ushort* __restrict__ S,
                                               const float* __restrict__ T,
                                               ushort* __restrict__ O,
                                               int nrows, int domix) {
    int wid = (int)((blockIdx.x * 256 + threadIdx.x) >> 6);
    int lane = threadIdx.x & 63;
    if (wid >= nrows) return;
    int beg = rowptr[wid], end = rowptr[wid + 1];
    float acc[8] = {0.f, 0.f, 0.f, 0.f, 0.f, 0.f, 0.f, 0.f};
    int e = beg;
    for (; e + 3 < end; e += 4) {
        int2 e0 = edges[e], e1 = edges[e + 1], e2 = edges[e + 2], e3 = edges[e + 3];
        float v0 = __int_as_float(e0.y), v1 = __int_as_float(e1.y);
        float v2 = __int_as_float(e2.y), v3 = __int_as_float(e3.y);
        s16x8 a = ((const s16x8*)(S + (size_t)e0.x * 512))[lane];
        s16x8 b = ((const s16x8*)(S + (size_t)e1.x * 512))[lane];
        s16x8 c = ((const s16x8*)(S + (size_t)e2.x * 512))[lane];
        s16x8 d = ((const s16x8*)(S + (size_t)e3.x * 512))[lane];
#pragma unroll
        for (int j = 0; j < 8; ++j)
            acc[j] += v0 * bf2f((ushort)a[j]) + v1 * bf2f((ushort)b[j])
                    + v2 * bf2f((ushort)c[j]) + v3 * bf2f((ushort)d[j]);
    }
    for (; e + 1 < end; e += 2) {
        int2 e0 = edges[e], e1 = edges[e + 1];
        float v0 = __int_as_float(e0.y), v1 = __int_as_float(e1.y);
        s16x8 a = ((const s16x8*)(S + (size_t)e0.x * 512))[lane];
        s16x8 b = ((const s16x8*)(S + (size_t)e1.x * 512))[lane];
#pragma unroll
        for (int j = 0; j < 8; ++j)
            acc[j] += v0 * bf2f((ushort)a[j]) + v1 * bf2f((ushort)b[j]);
    }
    if (e < end) {
        int2 e0 = edges[e];
        float v0 = __int_as_float(e0.y);
        s16x8 a = ((const s16x8*)(S + (size_t)e0.x * 512))[lane];
#pragma unroll
        for (int j = 0; j < 8; ++j)
            acc[j] += v0 * bf2f((ushort)a[j]);
    }
    int c0 = lane * 8;
    float res[8];
    if (domix) {
        float tv[8] = {0.f, 0.f, 0.f, 0.f, 0.f, 0.f, 0.f, 0.f};
        const float* trow = T + (size_t)wid * 500;
        if (c0 + 8 <= 500) {
            float4 t0 = *(const float4*)(trow + c0);
            float4 t1 = *(const float4*)(trow + c0 + 4);
            tv[0] = t0.x; tv[1] = t0.y; tv[2] = t0.z; tv[3] = t0.w;
            tv[4] = t1.x; tv[5] = t1.y; tv[6] = t1.z; tv[7] = t1.w;
        } else {
#pragma unroll
            for (int j = 0; j < 8; ++j)
                if (c0 + j < 500) tv[j] = trow[c0 + j];
        }
#pragma unroll
        for (int j = 0; j < 8; ++j)
            res[j] = (c0 + j < 500) ? (0.5f * fmaxf(acc[j], 0.f) + 0.5f * tv[j]) : 0.f;
    } else {
#pragma unroll
        for (int j = 0; j < 8; ++j)
            res[j] = (c0 + j < 500) ? acc[j] : 0.f;
    }
    s16x8 o;
#pragma unroll
    for (int j = 0; j < 8; ++j) o[j] = (short)f2bf(res[j]);
    ((s16x8*)(O + (size_t)wid * 512))[lane] = o;
}

// ---------------- SpMM gather, D=10 f32; optional fused mix+@W5 epilogue -------------
__global__ __launch_bounds__(256) void spmm10(const int* __restrict__ rowptr,
                                              const int2* __restrict__ edges,
                                              const float* __restrict__ S,
                                              const float* __restrict__ T,
                                              const float* __restrict__ W5,
                                              float* __restrict__ O, int nrows) {
    int g = (int)((blockIdx.x * 256 + threadIdx.x) >> 4);
    int t = threadIdx.x & 15;
    if (g >= nrows || t >= 10) return;
    int beg = rowptr[g], end = rowptr[g + 1];
    float acc = 0.f;
    for (int e = beg; e < end; ++e) {
        int2 ed = edges[e];
        acc += __int_as_float(ed.y) * S[(size_t)ed.x * 10 + t];
    }
    if (W5) {
        float m = 0.5f * fmaxf(acc, 0.f) + 0.5f * T[(size_t)g * 10 + t];
        float s5 = 0.f;
#pragma unroll
        for (int i = 0; i < 10; ++i)
            s5 += __shfl(m, i, 16) * W5[i * 10 + t];
        O[(size_t)g * 10 + t] = s5;
    } else {
        O[(size_t)g * 10 + t] = acc;
    }
}

extern "C" void kernel_launch(void* const* d_in, const int* in_sizes, int n_in,
                              void* d_out, int out_size, void* d_ws, size_t ws_size,
                              hipStream_t stream) {
    const float* x    = (const float*)d_in[0];
    const int*   ar   = (const int*)d_in[1];
    const int*   ac   = (const int*)d_in[2];
    const float* av   = (const float*)d_in[3];
    const float* tra1 = (const float*)d_in[4];
    const float* tra2 = (const float*)d_in[5];
    const float* tra3 = (const float*)d_in[6];
    const float* z    = (const float*)d_in[7];
    const float* W1   = (const float*)d_in[8];
    const float* W2   = (const float*)d_in[9];
    const float* W3   = (const float*)d_in[10];
    const float* W4   = (const float*)d_in[11];
    const float* W5   = (const float*)d_in[12];

    const int E = in_sizes[1];
    const int N = in_sizes[7] / 10;   // 50000
    const int NCH = (N + SCAN_CHUNK - 1) / SCAN_CHUNK;

    ushort* Abf    = (ushort*)d_ws;                     // [N,512] bf16
    ushort* Sbf    = Abf + (size_t)N * 512;             // [N,512] bf16
    ushort* Wt     = Sbf + (size_t)N * 512;             // [2048,512] bf16 (W1/W2/W3 in turn)
    float*  sup4   = (float*)(Wt + 2048 * 512);         // [N,10] f32
    float*  sup5   = sup4 + (size_t)N * 10;             // [N,10] f32
    float*  sup4p  = sup5 + (size_t)N * 10;             // [64][N*10] f32 partials (128 MB)
    int2*   edges  = (int2*)(sup4p + (size_t)64 * N * 10); // [E]
    int*    rowptr = (int*)(edges + E);                 // [N+1]
    int*    cnt    = rowptr + (N + 1);                  // [N]
    int*    csum   = cnt + N;                           // [NCH]
    float*  out    = (float*)d_out;

    dim3 blk(256);
    dim3 blk8(512);

    // ---- CSR build ----
    hipMemsetAsync(cnt, 0, (size_t)N * sizeof(int), stream);
    csr_count<<<(E + 255) / 256, blk, 0, stream>>>(ar, cnt, E);
    scan1<<<NCH, blk, 0, stream>>>(cnt, csum, N);
    scan2<<<1, 64, 0, stream>>>(csum, NCH);
    scan3<<<NCH, blk, 0, stream>>>(cnt, csum, rowptr, N, E);
    hipMemcpyAsync(cnt, rowptr, (size_t)N * sizeof(int), hipMemcpyDeviceToDevice, stream);
    csr_fill<<<(E + 255) / 256, blk, 0, stream>>>(ar, ac, av, cnt, edges, E);

    const int spmm_blocks   = (N * 64 + 255) / 256;
    const int spmm10_blocks = (N * 16 + 255) / 256;

    // ---- Layer 1: Abf = bf16(x); Sbf = Abf@W1t; Abf = mix(spmm(Sbf), tra1)
    cvt4<<<(int)(((long)N * 512 / 4 + 255) / 256), blk, 0, stream>>>(x, Abf, (long)N * 512 / 4);
    cvt_wt<<<(512 * 512 + 255) / 256, blk, 0, stream>>>(W1, Wt, 512, 500, 512);
    {
        dim3 g(4, (N + BM - 1) / BM);
        gemm_sup<<<g, blk8, 0, stream>>>(Abf, Wt, Sbf, N);
    }
    spmm_bf<<<spmm_blocks, blk, 0, stream>>>(rowptr, edges, Sbf, tra1, Abf, N, 1);

    // ---- Layer 2: Sbf = Abf@W2t; Abf(m2) = mix(spmm(Sbf), tra2)
    cvt_wt<<<(512 * 512 + 255) / 256, blk, 0, stream>>>(W2, Wt, 500, 500, 512);
    {
        dim3 g(4, (N + BM - 1) / BM);
        gemm_sup<<<g, blk8, 0, stream>>>(Abf, Wt, Sbf, N);
    }
    spmm_bf<<<spmm_blocks, blk, 0, stream>>>(rowptr, edges, Sbf, tra2, Abf, N, 1);

    // ---- Layer 3 (spmm-first, fused): Sbf(g) = spmm(m2) raw;
    //      sup4p = per-(colblock,kquarter) partials of (relu(g@W3)+tra3)@(0.5*W4);
    //      sup4 = sum of 64 partials
    spmm_bf<<<spmm_blocks, blk, 0, stream>>>(rowptr, edges, Abf, nullptr, Sbf, N, 0);
    cvt_wt<<<(2048 * 512 + 255) / 256, blk, 0, stream>>>(W3, Wt, 500, 2000, 2048);
    {
        dim3 g(16, (N + BM - 1) / BM);
        gemm3_w4<<<g, blk8, 0, stream>>>(Sbf, Wt, tra3, W4, sup4p, N);
    }
    sup4_reduce<<<(N * 10 + 255) / 256, blk, 0, stream>>>(sup4p, sup4, N * 10);

    // ---- Layer 4+5a: sup5 = (mix(spmm(sup4), z)) @ W5  (fused epilogue)
    spmm10<<<spmm10_blocks, blk, 0, stream>>>(rowptr, edges, sup4, z, W5, sup5, N);

    // ---- Layer 5b: out = spmm(sup5) raw
    spmm10<<<spmm10_blocks, blk, 0, stream>>>(rowptr, edges, sup5, nullptr, nullptr, out, N);
}

// Round 10
// 1349.263 us; speedup vs baseline: 1.1992x; 1.0533x over previous
//
#include <hip/hip_runtime.h>
#include <hip/hip_bf16.h>

// GNN: 5-layer GCN on MI355X. Round 10:
// - Counted-vmcnt 2-phase K-loop (T4-lite) in both MFMA GEMMs: raw s_barrier +
//   s_waitcnt vmcnt(4) keeps the next tile's 4 global_load_lds in flight across the
//   barrier (old __syncthreads drained vmcnt to 0 every iter). sched_barrier(0)
//   fences per rule #18.
// - gemm3_w4: 4 k-quarter waves combine stage-2 partials in LDS -> 16 global slots
//   (writes 125->31 MB); sup4_reduce sums 16.
// - All cvt kernels launched upfront.
// Unchanged: XOR-swizzle, mix-through-W4, 8-wave blocks, CSR-gather SpMM.

#define SCAN_CHUNK 512
#define BM 128
#define BN 128
#define BK 64

typedef __attribute__((ext_vector_type(4))) float f32x4;
typedef __attribute__((ext_vector_type(8))) __bf16 bf16x8;
typedef __attribute__((ext_vector_type(8))) short s16x8;

__device__ __forceinline__ bf16x8 as_bf(s16x8 v) { union { s16x8 s; bf16x8 b; } u; u.s = v; return u.b; }
__device__ __forceinline__ ushort f2bf(float f) {
    uint u = __float_as_uint(f);
    return (ushort)((u + 0x7FFFu + ((u >> 16) & 1u)) >> 16);   // RNE
}
__device__ __forceinline__ float bf2f(ushort s) { return __uint_as_float(((uint)s) << 16); }

#define GLL16(g, l)                                                                 \
    __builtin_amdgcn_global_load_lds((const __attribute__((address_space(1))) void*)(g), \
                                     (__attribute__((address_space(3))) void*)(l), 16, 0, 0)

// 8-wave staging: 4 GLL per thread per stage (2 iters x {A,B})
#define STAGE_TILE8(k0, base)                                                       \
    _Pragma("unroll")                                                               \
    for (int i = 0; i < 2; ++i) {                                                   \
        int ar = row0 + arow_off + i * 64;                                          \
        if (ar >= M) ar = M - 1;                                                    \
        GLL16(A + (size_t)ar * 512 + (k0) + acol, &lds[(base) + (w * 8 + i * 64) * BK]); \
        GLL16(Bt + (size_t)(col0 + arow_off + i * 64) * 512 + (k0) + acol,          \
              &lds[(base) + 8192 + (w * 8 + i * 64) * BK]);                         \
    }

// wave w computes 64x32: wr=(w>>2)*64, wc=(w&3)*32; fragments 4(m) x 2(n)
#define COMPUTE_TILE8(base)                                                         \
    _Pragma("unroll")                                                               \
    for (int s = 0; s < 2; ++s) {                                                   \
        int cswz = (((s * 4 + (l >> 4)) ^ (l & 7)) << 3);                           \
        bf16x8 af[4], bfr[2];                                                       \
        _Pragma("unroll")                                                           \
        for (int m = 0; m < 4; ++m)                                                 \
            af[m] = as_bf(*(const s16x8*)&lds[(base) + (wr + m * 16 + (l & 15)) * BK + cswz]); \
        _Pragma("unroll")                                                           \
        for (int n = 0; n < 2; ++n)                                                 \
            bfr[n] = as_bf(*(const s16x8*)&lds[(base) + 8192 + (wc + n * 16 + (l & 15)) * BK + cswz]); \
        _Pragma("unroll")                                                           \
        for (int m = 0; m < 4; ++m)                                                 \
            _Pragma("unroll")                                                       \
            for (int n = 0; n < 2; ++n)                                             \
                acc[m][n] = __builtin_amdgcn_mfma_f32_16x16x32_bf16(af[m], bfr[n], acc[m][n], 0, 0, 0); \
    }

// counted-vmcnt 2-phase K-loop: never drain vmcnt to 0 mid-loop
#define KLOOP_PIPELINED()                                                           \
    STAGE_TILE8(0, 0);                                                              \
    int base = 0;                                                                   \
    _Pragma("unroll 1")                                                             \
    for (int t = 0; t < 8; ++t) {                                                   \
        if (t < 7) {                                                                \
            STAGE_TILE8((t + 1) * BK, base ^ 16384);                                \
            asm volatile("s_waitcnt vmcnt(4)" ::: "memory");                        \
        } else {                                                                    \
            asm volatile("s_waitcnt vmcnt(0)" ::: "memory");                        \
        }                                                                           \
        __builtin_amdgcn_s_barrier();                                               \
        __builtin_amdgcn_sched_barrier(0);                                          \
        COMPUTE_TILE8(base);                                                        \
        __builtin_amdgcn_sched_barrier(0);                                          \
        __builtin_amdgcn_s_barrier();                                               \
        base ^= 16384;                                                              \
    }

// ---------------- support GEMM: C[M,512]bf16 = A[M,512]bf16 @ Bt[512,512]bf16^T ------
__global__ __launch_bounds__(512) void gemm_sup(const ushort* __restrict__ A,
                                                const ushort* __restrict__ Bt,
                                                ushort* __restrict__ C, int M) {
    __shared__ ushort lds[32768];   // 64 KB: double-buffered As/Bs
    int tid = threadIdx.x;
    int w = tid >> 6, l = tid & 63;
    int row0 = blockIdx.y * BM, col0 = blockIdx.x * BN;
    int wr = (w >> 2) * 64, wc = (w & 3) * 32;
    f32x4 acc[4][2] = {};
    int arow_off = w * 8 + (l >> 3);
    int acol = (((l & 7) ^ (l >> 3)) << 3);

    KLOOP_PIPELINED();

    int crow = (l >> 4) * 4, ccol = l & 15;
#pragma unroll
    for (int m = 0; m < 4; ++m)
#pragma unroll
        for (int n = 0; n < 2; ++n) {
            int gc = col0 + wc + n * 16 + ccol;
#pragma unroll
            for (int r = 0; r < 4; ++r) {
                int gr = row0 + wr + m * 16 + crow + r;
                if (gr < M) C[(size_t)gr * 512 + gc] = f2bf(acc[m][n][r]);
            }
        }
}

// ---------------- fused layer-3: partial = (relu(g@W3) + tra3) @ (0.5*W4) ------------
// 8 waves; stage-2 K (=128) split across the 4 wc-waves; partials combined in LDS ->
// one slot per col-block (16 slots).
__global__ __launch_bounds__(512) void gemm3_w4(const ushort* __restrict__ A,
                                                const ushort* __restrict__ Bt,
                                                const float* __restrict__ T,
                                                const float* __restrict__ W4,
                                                float* __restrict__ sup4p, int M) {
    __shared__ ushort lds[32768];   // 64 KB dbuf; epilogue overlays
    int tid = threadIdx.x;
    int w = tid >> 6, l = tid & 63;
    int row0 = blockIdx.y * BM, col0 = blockIdx.x * BN;
    int wr = (w >> 2) * 64, wc = (w & 3) * 32;
    int crow = (l >> 4) * 4, ccol = l & 15;

    // B-frag of 0.5*W4 in registers; this wave's k-quarter
    bf16x8 w4f;
    {
        s16x8 tmp;
#pragma unroll
        for (int kk = 0; kk < 8; ++kk) {
            int gk = col0 + (w & 3) * 32 + ((l >> 4) << 3) + kk;
            float v = (ccol < 10 && gk < 2000) ? 0.5f * W4[(size_t)gk * 10 + ccol] : 0.f;
            tmp[kk] = (short)f2bf(v);
        }
        w4f = as_bf(tmp);
    }

    f32x4 acc[4][2] = {};
    int arow_off = w * 8 + (l >> 3);
    int acol = (((l & 7) ^ (l >> 3)) << 3);

    KLOOP_PIPELINED();

    ushort* actS = lds;   // [128][128] swizzled, overlays buffer 0

    // ---- epilogue A: relu(acc) -> actS (fragment writes, swizzled)
    __syncthreads();
#pragma unroll
    for (int m = 0; m < 4; ++m)
#pragma unroll
        for (int n = 0; n < 2; ++n) {
            int cl = wc + n * 16 + ccol;
            int cch = cl >> 3, clo = cl & 7;
#pragma unroll
            for (int r = 0; r < 4; ++r) {
                int rl = wr + m * 16 + crow + r;
                actS[rl * 128 + (((cch ^ (rl & 7)) << 3) | clo)] = f2bf(fmaxf(acc[m][n][r], 0.f));
            }
        }
    __syncthreads();

    // ---- stage-2a: relu-part @ 0.5W4 (this wave's 64 rows x its 32-k quarter)
    f32x4 acc2[4] = {};
    {
        int chunk = (w & 3) * 4 + (l >> 4);
#pragma unroll
        for (int m = 0; m < 4; ++m) {
            int row = wr + m * 16 + ccol;
            bf16x8 af = as_bf(*(const s16x8*)&actS[row * 128 + ((chunk ^ (row & 7)) << 3)]);
            acc2[m] = __builtin_amdgcn_mfma_f32_16x16x32_bf16(af, w4f, acc2[m], 0, 0, 0);
        }
    }
    __syncthreads();   // done reading relu tile

    // ---- epilogue B: tra3 tile -> actS, COALESCED (float4 per thread, 8 rounds)
    {
        int r_off = tid >> 5;            // 0..15
        int c4 = (tid & 31) * 4;
        int chunk = (tid & 31) >> 1;
        int lo = (tid & 1) * 4;
#pragma unroll
        for (int p = 0; p < 8; ++p) {
            int rl = p * 16 + r_off;
            int gr = row0 + rl;
            int gcb = col0 + c4;
            ushort4 h;
            if (gr < M && gcb + 3 < 2000) {
                float4 tv = *(const float4*)(T + (size_t)gr * 2000 + gcb);
                h.x = f2bf(tv.x); h.y = f2bf(tv.y); h.z = f2bf(tv.z); h.w = f2bf(tv.w);
            } else {
                float e[4];
#pragma unroll
                for (int i = 0; i < 4; ++i)
                    e[i] = (gr < M && gcb + i < 2000) ? T[(size_t)gr * 2000 + gcb + i] : 0.f;
                h.x = f2bf(e[0]); h.y = f2bf(e[1]); h.z = f2bf(e[2]); h.w = f2bf(e[3]);
            }
            *(ushort4*)&actS[rl * 128 + ((chunk ^ (rl & 7)) << 3) + lo] = h;
        }
    }
    __syncthreads();

    // ---- stage-2b: tra3-part @ 0.5W4 (accumulate into acc2)
    {
        int chunk = (w & 3) * 4 + (l >> 4);
#pragma unroll
        for (int m = 0; m < 4; ++m) {
            int row = wr + m * 16 + ccol;
            bf16x8 af = as_bf(*(const s16x8*)&actS[row * 128 + ((chunk ^ (row & 7)) << 3)]);
            acc2[m] = __builtin_amdgcn_mfma_f32_16x16x32_bf16(af, w4f, acc2[m], 0, 0, 0);
        }
    }
    __syncthreads();   // all waves done reading actS

    // ---- combine 4 k-quarters in LDS, write ONE slot per block
    float* redS = (float*)lds;   // [4][128][16] f32 = 32 KB
    {
        int q = w & 3;
#pragma unroll
        for (int m = 0; m < 4; ++m)
#pragma unroll
            for (int r = 0; r < 4; ++r) {
                int row = wr + m * 16 + crow + r;
                redS[(q * 128 + row) * 16 + ccol] = acc2[m][r];
            }
    }
    __syncthreads();
    {
        float* dst = sup4p + (size_t)blockIdx.x * ((size_t)M * 10);
#pragma unroll
        for (int p = 0; p < 4; ++p) {
            int o = p * 512 + tid;       // 0..2047
            int row = o >> 4, col = o & 15;
            int gr = row0 + row;
            if (col < 10 && gr < M) {
                float s = redS[(0 * 128 + row) * 16 + col] + redS[(1 * 128 + row) * 16 + col]
                        + redS[(2 * 128 + row) * 16 + col] + redS[(3 * 128 + row) * 16 + col];
                dst[(size_t)gr * 10 + col] = s;
            }
        }
    }
}

// ---------------- sum 16 partial slots -> sup4 ----------------
__global__ __launch_bounds__(256) void sup4_reduce(const float* __restrict__ P,
                                                   float* __restrict__ O, int n) {
    int i = blockIdx.x * 256 + threadIdx.x;
    if (i >= n) return;
    float s = 0.f;
#pragma unroll
    for (int j = 0; j < 16; ++j) s += P[(size_t)j * n + i];
    O[i] = s;
}

// ---------------- conversions ----------------
__global__ __launch_bounds__(256) void cvt4(const float* __restrict__ s,
                                            ushort* __restrict__ d, long n4) {
    long i = (long)blockIdx.x * 256 + threadIdx.x;
    if (i >= n4) return;
    float4 v = ((const float4*)s)[i];
    ushort4 o = { f2bf(v.x), f2bf(v.y), f2bf(v.z), f2bf(v.w) };
    ((ushort4*)d)[i] = o;
}

// Wt[n][k] (Npad x 512) = bf16(W[k][n]), zero-padded
__global__ __launch_bounds__(256) void cvt_wt(const float* __restrict__ W,
                                              ushort* __restrict__ Wt,
                                              int Ksrc, int Nsrc, int Npad) {
    int i = blockIdx.x * 256 + threadIdx.x;
    if (i >= Npad * 512) return;
    int n = i >> 9, k = i & 511;
    float v = (k < Ksrc && n < Nsrc) ? W[(size_t)k * Nsrc + n] : 0.f;
    Wt[i] = f2bf(v);
}

// ---------------- CSR build: count / scan / fill ----------------
__global__ __launch_bounds__(256) void csr_count(const int* __restrict__ rows,
                                                 int* __restrict__ cnt, int E) {
    int e = blockIdx.x * 256 + threadIdx.x;
    if (e < E) atomicAdd(&cnt[rows[e]], 1);
}

__global__ __launch_bounds__(256) void scan1(const int* __restrict__ cnt,
                                             int* __restrict__ csum, int n) {
    __shared__ int red[256];
    int base = blockIdx.x * SCAN_CHUNK;
    int t = threadIdx.x;
    int s = 0;
    if (base + t < n) s += cnt[base + t];
    if (base + t + 256 < n) s += cnt[base + t + 256];
    red[t] = s;
    __syncthreads();
    for (int off = 128; off; off >>= 1) {
        if (t < off) red[t] += red[t + off];
        __syncthreads();
    }
    if (t == 0) csum[blockIdx.x] = red[0];
}

__global__ void scan2(int* csum, int nch) {
    if (threadIdx.x == 0 && blockIdx.x == 0) {
        int acc = 0;
        for (int i = 0; i < nch; ++i) { int v = csum[i]; csum[i] = acc; acc += v; }
    }
}

__global__ __launch_bounds__(256) void scan3(const int* __restrict__ cnt,
                                             const int* __restrict__ csum,
                                             int* __restrict__ rowptr, int n, int E) {
    __shared__ int sm[SCAN_CHUNK];
    int base = blockIdx.x * SCAN_CHUNK;
    int t = threadIdx.x;
    for (int i = t; i < SCAN_CHUNK; i += 256) sm[i] = (base + i < n) ? cnt[base + i] : 0;
    __syncthreads();
    for (int off = 1; off < SCAN_CHUNK; off <<= 1) {
        int i0 = t, i1 = t + 256;
        int v0 = (i0 >= off) ? sm[i0 - off] : 0;
        int v1 = (i1 >= off) ? sm[i1 - off] : 0;
        __syncthreads();
        sm[i0] += v0;
        sm[i1] += v1;
        __syncthreads();
    }
    int off0 = csum[blockIdx.x];
    for (int i = t; i < SCAN_CHUNK; i += 256)
        if (base + i < n) rowptr[base + i] = off0 + (i ? sm[i - 1] : 0);
    if (blockIdx.x == 0 && t == 0) rowptr[n] = E;
}

__global__ __launch_bounds__(256) void csr_fill(const int* __restrict__ rows,
                                                const int* __restrict__ cols,
                                                const float* __restrict__ vals,
                                                int* __restrict__ cur,
                                                int2* __restrict__ edges, int E) {
    int e = blockIdx.x * 256 + threadIdx.x;
    if (e >= E) return;
    int p = atomicAdd(&cur[rows[e]], 1);
    edges[p] = make_int2(cols[e], __float_as_int(vals[e]));
}

// ---------------- SpMM gather, bf16 source [nrows,512]: wave per row, 4-edge unroll --
__global__ __launch_bounds__(256) void spmm_bf(const int* __restrict__ rowptr,
                                               const int2* __restrict__ edges,
                                               const ushort* __restrict__ S,
                                               const float* __restrict__ T,
                                               ushort* __restrict__ O,
                                               int nrows, int domix) {
    int wid = (int)((blockIdx.x * 256 + threadIdx.x) >> 6);
    int lane = threadIdx.x & 63;
    if (wid >= nrows) return;
    int beg = rowptr[wid], end = rowptr[wid + 1];
    float acc[8] = {0.f, 0.f, 0.f, 0.f, 0.f, 0.f, 0.f, 0.f};
    int e = beg;
    for (; e + 3 < end; e += 4) {
        int2 e0 = edges[e], e1 = edges[e + 1], e2 = edges[e + 2], e3 = edges[e + 3];
        float v0 = __int_as_float(e0.y), v1 = __int_as_float(e1.y);
        float v2 = __int_as_float(e2.y), v3 = __int_as_float(e3.y);
        s16x8 a = ((const s16x8*)(S + (size_t)e0.x * 512))[lane];
        s16x8 b = ((const s16x8*)(S + (size_t)e1.x * 512))[lane];
        s16x8 c = ((const s16x8*)(S + (size_t)e2.x * 512))[lane];
        s16x8 d = ((const s16x8*)(S + (size_t)e3.x * 512))[lane];
#pragma unroll
        for (int j = 0; j < 8; ++j)
            acc[j] += v0 * bf2f((ushort)a[j]) + v1 * bf2f((ushort)b[j])
                    + v2 * bf2f((ushort)c[j]) + v3 * bf2f((ushort)d[j]);
    }
    for (; e + 1 < end; e += 2) {
        int2 e0 = edges[e], e1 = edges[e + 1];
        float v0 = __int_as_float(e0.y), v1 = __int_as_float(e1.y);
        s16x8 a = ((const s16x8*)(S + (size_t)e0.x * 512))[lane];
        s16x8 b = ((const s16x8*)(S + (size_t)e1.x * 512))[lane];
#pragma unroll
        for (int j = 0; j < 8; ++j)
            acc[j] += v0 * bf2f((ushort)a[j]) + v1 * bf2f((ushort)b[j]);
    }
    if (e < end) {
        int2 e0 = edges[e];
        float v0 = __int_as_float(e0.y);
        s16x8 a = ((const s16x8*)(S + (size_t)e0.x * 512))[lane];
#pragma unroll
        for (int j = 0; j < 8; ++j)
            acc[j] += v0 * bf2f((ushort)a[j]);
    }
    int c0 = lane * 8;
    float res[8];
    if (domix) {
        float tv[8] = {0.f, 0.f, 0.f, 0.f, 0.f, 0.f, 0.f, 0.f};
        const float* trow = T + (size_t)wid * 500;
        if (c0 + 8 <= 500) {
            float4 t0 = *(const float4*)(trow + c0);
            float4 t1 = *(const float4*)(trow + c0 + 4);
            tv[0] = t0.x; tv[1] = t0.y; tv[2] = t0.z; tv[3] = t0.w;
            tv[4] = t1.x; tv[5] = t1.y; tv[6] = t1.z; tv[7] = t1.w;
        } else {
#pragma unroll
            for (int j = 0; j < 8; ++j)
                if (c0 + j < 500) tv[j] = trow[c0 + j];
        }
#pragma unroll
        for (int j = 0; j < 8; ++j)
            res[j] = (c0 + j < 500) ? (0.5f * fmaxf(acc[j], 0.f) + 0.5f * tv[j]) : 0.f;
    } else {
#pragma unroll
        for (int j = 0; j < 8; ++j)
            res[j] = (c0 + j < 500) ? acc[j] : 0.f;
    }
    s16x8 o;
#pragma unroll
    for (int j = 0; j < 8; ++j) o[j] = (short)f2bf(res[j]);
    ((s16x8*)(O + (size_t)wid * 512))[lane] = o;
}

// ---------------- SpMM gather, D=10 f32; optional fused mix+@W5 epilogue -------------
__global__ __launch_bounds__(256) void spmm10(const int* __restrict__ rowptr,
                                              const int2* __restrict__ edges,
                                              const float* __restrict__ S,
                                              const float* __restrict__ T,
                                              const float* __restrict__ W5,
                                              float* __restrict__ O, int nrows) {
    int g = (int)((blockIdx.x * 256 + threadIdx.x) >> 4);
    int t = threadIdx.x & 15;
    if (g >= nrows || t >= 10) return;
    int beg = rowptr[g], end = rowptr[g + 1];
    float acc = 0.f;
    for (int e = beg; e < end; ++e) {
        int2 ed = edges[e];
        acc += __int_as_float(ed.y) * S[(size_t)ed.x * 10 + t];
    }
    if (W5) {
        float m = 0.5f * fmaxf(acc, 0.f) + 0.5f * T[(size_t)g * 10 + t];
        float s5 = 0.f;
#pragma unroll
        for (int i = 0; i < 10; ++i)
            s5 += __shfl(m, i, 16) * W5[i * 10 + t];
        O[(size_t)g * 10 + t] = s5;
    } else {
        O[(size_t)g * 10 + t] = acc;
    }
}

extern "C" void kernel_launch(void* const* d_in, const int* in_sizes, int n_in,
                              void* d_out, int out_size, void* d_ws, size_t ws_size,
                              hipStream_t stream) {
    const float* x    = (const float*)d_in[0];
    const int*   ar   = (const int*)d_in[1];
    const int*   ac   = (const int*)d_in[2];
    const float* av   = (const float*)d_in[3];
    const float* tra1 = (const float*)d_in[4];
    const float* tra2 = (const float*)d_in[5];
    const float* tra3 = (const float*)d_in[6];
    const float* z    = (const float*)d_in[7];
    const float* W1   = (const float*)d_in[8];
    const float* W2   = (const float*)d_in[9];
    const float* W3   = (const float*)d_in[10];
    const float* W4   = (const float*)d_in[11];
    const float* W5   = (const float*)d_in[12];

    const int E = in_sizes[1];
    const int N = in_sizes[7] / 10;   // 50000
    const int NCH = (N + SCAN_CHUNK - 1) / SCAN_CHUNK;

    ushort* Abf    = (ushort*)d_ws;                     // [N,512] bf16
    ushort* Sbf    = Abf + (size_t)N * 512;             // [N,512] bf16
    ushort* Wt1    = Sbf + (size_t)N * 512;             // [512,512] bf16
    ushort* Wt2    = Wt1 + 512 * 512;                   // [512,512] bf16
    ushort* Wt3    = Wt2 + 512 * 512;                   // [2048,512] bf16
    float*  sup4   = (float*)(Wt3 + 2048 * 512);        // [N,10] f32
    float*  sup5   = sup4 + (size_t)N * 10;             // [N,10] f32
    float*  sup4p  = sup5 + (size_t)N * 10;             // [16][N*10] f32 partials (32 MB)
    int2*   edges  = (int2*)(sup4p + (size_t)16 * N * 10); // [E]
    int*    rowptr = (int*)(edges + E);                 // [N+1]
    int*    cnt    = rowptr + (N + 1);                  // [N]
    int*    csum   = cnt + N;                           // [NCH]
    float*  out    = (float*)d_out;

    dim3 blk(256);
    dim3 blk8(512);

    // ---- all conversions upfront (independent) ----
    cvt4<<<(int)(((long)N * 512 / 4 + 255) / 256), blk, 0, stream>>>(x, Abf, (long)N * 512 / 4);
    cvt_wt<<<(512 * 512 + 255) / 256, blk, 0, stream>>>(W1, Wt1, 512, 500, 512);
    cvt_wt<<<(512 * 512 + 255) / 256, blk, 0, stream>>>(W2, Wt2, 500, 500, 512);
    cvt_wt<<<(2048 * 512 + 255) / 256, blk, 0, stream>>>(W3, Wt3, 500, 2000, 2048);

    // ---- CSR build ----
    hipMemsetAsync(cnt, 0, (size_t)N * sizeof(int), stream);
    csr_count<<<(E + 255) / 256, blk, 0, stream>>>(ar, cnt, E);
    scan1<<<NCH, blk, 0, stream>>>(cnt, csum, N);
    scan2<<<1, 64, 0, stream>>>(csum, NCH);
    scan3<<<NCH, blk, 0, stream>>>(cnt, csum, rowptr, N, E);
    hipMemcpyAsync(cnt, rowptr, (size_t)N * sizeof(int), hipMemcpyDeviceToDevice, stream);
    csr_fill<<<(E + 255) / 256, blk, 0, stream>>>(ar, ac, av, cnt, edges, E);

    const int spmm_blocks   = (N * 64 + 255) / 256;
    const int spmm10_blocks = (N * 16 + 255) / 256;

    // ---- Layer 1: Sbf = Abf@W1t; Abf = mix(spmm(Sbf), tra1)
    {
        dim3 g(4, (N + BM - 1) / BM);
        gemm_sup<<<g, blk8, 0, stream>>>(Abf, Wt1, Sbf, N);
    }
    spmm_bf<<<spmm_blocks, blk, 0, stream>>>(rowptr, edges, Sbf, tra1, Abf, N, 1);

    // ---- Layer 2: Sbf = Abf@W2t; Abf(m2) = mix(spmm(Sbf), tra2)
    {
        dim3 g(4, (N + BM - 1) / BM);
        gemm_sup<<<g, blk8, 0, stream>>>(Abf, Wt2, Sbf, N);
    }
    spmm_bf<<<spmm_blocks, blk, 0, stream>>>(rowptr, edges, Sbf, tra2, Abf, N, 1);

    // ---- Layer 3 (spmm-first, fused): Sbf(g) = spmm(m2) raw;
    //      sup4p[16 slots] = (relu(g@W3)+tra3)@(0.5*W4) partials; sup4 = sum
    spmm_bf<<<spmm_blocks, blk, 0, stream>>>(rowptr, edges, Abf, nullptr, Sbf, N, 0);
    {
        dim3 g(16, (N + BM - 1) / BM);
        gemm3_w4<<<g, blk8, 0, stream>>>(Sbf, Wt3, tra3, W4, sup4p, N);
    }
    sup4_reduce<<<(N * 10 + 255) / 256, blk, 0, stream>>>(sup4p, sup4, N * 10);

    // ---- Layer 4+5a: sup5 = (mix(spmm(sup4), z)) @ W5  (fused epilogue)
    spmm10<<<spmm10_blocks, blk, 0, stream>>>(rowptr, edges, sup4, z, W5, sup5, N);

    // ---- Layer 5b: out = spmm(sup5) raw
    spmm10<<<spmm10_blocks, blk, 0, stream>>>(rowptr, edges, sup5, nullptr, nullptr, out, N);
}